// Round 5
// baseline (476.406 us; speedup 1.0000x reference)
//
#include <hip/hip_runtime.h>
#include <hip/hip_cooperative_groups.h>

namespace cg = cooperative_groups;

// 3D reaction-diffusion tumor solver, 160^3 f32 grid, 30 explicit Euler steps.
// R7: persistent cooperative kernel — full occupancy + register z-neighbors.
//
// R6 post-mortem (471 us timed): register residency fixed (VGPR=40, clean),
// but occupancy 47.8% is the cap — grid was 500 blocks = 16 waves/CU, and
// the post-barrier acquire fence invalidates L2 so every step's reads carry
// L3 latency; VALUBusy 6.7% = latency-bound. R7:
//   - GPT=2 with CONTIGUOUS z-pairs (planes 2k,2k+1 per thread): intra-pair
//     z-neighbors come from the thread's own cv registers -> global reads
//     drop 72B -> 56B per 16B output (-22%)
//   - 1000 blocks x 512 threads = 31 waves/CU (2x R6), launch_bounds(512,8)
//     caps VGPR at 64 (state = 16 regs, fits)
//   - XCD swizzle: 1000%8==0, each XCD owns a contiguous 20-plane z-slab
// Barrier unchanged from R6 (distributed arrive flags + per-XCD go lines).

#define NX 160
#define NY 160
#define NZ 160
#define NXQ (NX / 4)              // 40 float4 groups per row
#define NPLANE (NX * NY)          // 25600 floats per z-plane
#define NGROUPS (NZ * NY * NXQ)   // 1,024,000 float4 groups

// --- cooperative config: 512-thread blocks, contiguous z-pairs ---
#define CT_BS 512
#define CT_NTHREADS (NGROUPS / 2)        // 512,000
#define CT_NBLOCKS (CT_NTHREADS / CT_BS) // 1000

// --- fallback config (R2): 2 groups/thread, strided halves ---
#define FB_NTHREADS (NGROUPS / 2)      // 512,000
#define FB_NBLOCKS (FB_NTHREADS / 256) // 2000

// ---- barrier state (zero-init at module load; epochs monotonic forever) ----
__device__ unsigned int g_arrive[CT_NBLOCKS * 16];  // one flag per 64B line
__device__ unsigned int g_go[8 * 16];               // per-XCD go lines
__device__ unsigned int g_epoch_base;

__device__ __forceinline__ void grid_barrier(unsigned int e) {
    __syncthreads();  // all block threads' stores issued (vmcnt drained)
    const int bid = blockIdx.x;
    const int tid = threadIdx.x;
    if (bid == 0) {
        if (tid == 0) {
            __hip_atomic_store(&g_arrive[0], e, __ATOMIC_RELEASE,
                               __HIP_MEMORY_SCOPE_AGENT);
        }
        // parallel scan of all arrive flags, relaxed (cheap) polling
        for (int j = tid; j < CT_NBLOCKS; j += CT_BS) {
            while (__hip_atomic_load(&g_arrive[j * 16], __ATOMIC_RELAXED,
                                     __HIP_MEMORY_SCOPE_AGENT) < e) {}
        }
        __syncthreads();
        if (tid == 0) {
            __builtin_amdgcn_fence(__ATOMIC_ACQUIRE, "agent");
#pragma unroll
            for (int x = 0; x < 8; ++x) {
                __hip_atomic_store(&g_go[x * 16], e, __ATOMIC_RELEASE,
                                   __HIP_MEMORY_SCOPE_AGENT);
            }
        }
        __syncthreads();
    } else {
        if (tid == 0) {
            __hip_atomic_store(&g_arrive[bid * 16], e, __ATOMIC_RELEASE,
                               __HIP_MEMORY_SCOPE_AGENT);
            while (__hip_atomic_load(&g_go[(bid & 7) * 16], __ATOMIC_RELAXED,
                                     __HIP_MEMORY_SCOPE_AGENT) < e) {
                __builtin_amdgcn_s_sleep(1);
            }
            __builtin_amdgcn_fence(__ATOMIC_ACQUIRE, "agent");
        }
        __syncthreads();
    }
}

__device__ __forceinline__ float4 ld4(const float* p) {
    return *reinterpret_cast<const float4*>(p);
}

// ---------------- cooperative all-steps kernel ----------------
__global__ __launch_bounds__(CT_BS, 8) void therapy_all(
    const float* __restrict__ c_init,
    const float* __restrict__ ther,
    float* __restrict__ out,
    float* __restrict__ ws,
    const float* __restrict__ Dp,
    const float* __restrict__ rhop,
    const float* __restrict__ dtp,
    const int* __restrict__ stepsp)
{
    // Bijective XCD swizzle: dispatch round-robins XCDs (xcd = bid%8);
    // remap so each XCD owns a CONTIGUOUS logical range (= contiguous
    // 20-plane z-slab) -> halo reads mostly hit the local XCD L2.
    const int lb  = (blockIdx.x & 7) * (CT_NBLOCKS / 8) + (blockIdx.x >> 3);
    const int tid = lb * CT_BS + threadIdx.x;

    const int xq = tid % NXQ;
    const int t2 = tid / NXQ;
    const int y  = t2 % NY;
    const int k  = t2 / NY;            // z-pair index, planes 2k and 2k+1

    const int   steps   = *stepsp;
    const float D       = *Dp;
    const float rho     = *rhop;
    const float delta_t = *dtp / (float)steps;

    // epoch base from previous launch (coherent at kernel-dispatch boundary)
    const unsigned int ebase = g_epoch_base;

    const int  offym = (y > 0)        ? -NX : 0;
    const int  offyp = (y < NY - 1)   ?  NX : 0;
    const int  offxl = (xq > 0)       ? -1  : 0;
    const int  offxr = (xq < NXQ - 1) ?  4  : 3;
    const bool mym = (y == 0), myp = (y == NY - 1);
    const bool mxl = (xq == 0), mxr = (xq == NXQ - 1);
    const bool mzm = (k == 0);                    // plane 2k   is z==0
    const bool mzp = (k == NZ / 2 - 1);           // plane 2k+1 is z==159
    const int  offzm = mzm ? 0 : -NPLANE;
    const int  offzp = mzp ? 0 :  NPLANE;

    const int b0 = (2 * k * NY + y) * NX + xq * 4;  // plane 2k
    const int b1 = b0 + NPLANE;                     // plane 2k+1

    // Persistent register state: therapy + current concentration (16 VGPRs).
    const float4 tv0 = ld4(ther + b0);
    const float4 tv1 = ld4(ther + b1);
    float4 cv0 = ld4(c_init + b0);
    float4 cv1 = ld4(c_init + b1);

    const float4 z4 = make_float4(0.f, 0.f, 0.f, 0.f);

    const float* rd = c_init;
    for (int i = 0; i < steps; ++i) {
        // Ping-pong so the final step lands in `out` for any step count.
        float* wr = ((steps - 1 - i) & 1) ? ws : out;

        // ---- all global loads up front (max MLP) ----
        float4 ym0 = ld4(rd + b0 + offym);
        float4 yp0 = ld4(rd + b0 + offyp);
        float4 ym1 = ld4(rd + b1 + offym);
        float4 yp1 = ld4(rd + b1 + offyp);
        float4 zmg = ld4(rd + b0 + offzm);   // plane 2k-1 (masked at z=0)
        float4 zpg = ld4(rd + b1 + offzp);   // plane 2k+2 (masked at z=159)
        float  xl0 = rd[b0 + offxl];
        float  xr0 = rd[b0 + offxr];
        float  xl1 = rd[b1 + offxl];
        float  xr1 = rd[b1 + offxr];

        if (mym) { ym0 = z4; ym1 = z4; }
        if (myp) { yp0 = z4; yp1 = z4; }
        if (mzm) zmg = z4;
        if (mzp) zpg = z4;
        if (mxl) { xl0 = 0.f; xl1 = 0.f; }
        if (mxr) { xr0 = 0.f; xr1 = 0.f; }

        // ---- group 0 (plane 2k): zm = zmg, zp = cv1 (register) ----
        float4 n0;
        {
            const float lap0 = xl0   + cv0.y + ym0.x + yp0.x + zmg.x + cv1.x - 6.f * cv0.x;
            const float lap1 = cv0.x + cv0.z + ym0.y + yp0.y + zmg.y + cv1.y - 6.f * cv0.y;
            const float lap2 = cv0.y + cv0.w + ym0.z + yp0.z + zmg.z + cv1.z - 6.f * cv0.z;
            const float lap3 = cv0.z + xr0   + ym0.w + yp0.w + zmg.w + cv1.w - 6.f * cv0.w;
            float g;
            g = D * lap0 + rho * cv0.x * (1.f - cv0.x) - 2.f * tv0.x * cv0.x;
            n0.x = fminf(fmaxf(cv0.x + g * delta_t, 0.f), 1.f);
            g = D * lap1 + rho * cv0.y * (1.f - cv0.y) - 2.f * tv0.y * cv0.y;
            n0.y = fminf(fmaxf(cv0.y + g * delta_t, 0.f), 1.f);
            g = D * lap2 + rho * cv0.z * (1.f - cv0.z) - 2.f * tv0.z * cv0.z;
            n0.z = fminf(fmaxf(cv0.z + g * delta_t, 0.f), 1.f);
            g = D * lap3 + rho * cv0.w * (1.f - cv0.w) - 2.f * tv0.w * cv0.w;
            n0.w = fminf(fmaxf(cv0.w + g * delta_t, 0.f), 1.f);
        }
        // ---- group 1 (plane 2k+1): zm = cv0 (register), zp = zpg ----
        float4 n1;
        {
            const float lap0 = xl1   + cv1.y + ym1.x + yp1.x + cv0.x + zpg.x - 6.f * cv1.x;
            const float lap1 = cv1.x + cv1.z + ym1.y + yp1.y + cv0.y + zpg.y - 6.f * cv1.y;
            const float lap2 = cv1.y + cv1.w + ym1.z + yp1.z + cv0.z + zpg.z - 6.f * cv1.z;
            const float lap3 = cv1.z + xr1   + ym1.w + yp1.w + cv0.w + zpg.w - 6.f * cv1.w;
            float g;
            g = D * lap0 + rho * cv1.x * (1.f - cv1.x) - 2.f * tv1.x * cv1.x;
            n1.x = fminf(fmaxf(cv1.x + g * delta_t, 0.f), 1.f);
            g = D * lap1 + rho * cv1.y * (1.f - cv1.y) - 2.f * tv1.y * cv1.y;
            n1.y = fminf(fmaxf(cv1.y + g * delta_t, 0.f), 1.f);
            g = D * lap2 + rho * cv1.z * (1.f - cv1.z) - 2.f * tv1.z * cv1.z;
            n1.z = fminf(fmaxf(cv1.z + g * delta_t, 0.f), 1.f);
            g = D * lap3 + rho * cv1.w * (1.f - cv1.w) - 2.f * tv1.w * cv1.w;
            n1.w = fminf(fmaxf(cv1.w + g * delta_t, 0.f), 1.f);
        }

        *reinterpret_cast<float4*>(wr + b0) = n0;  cv0 = n0;
        *reinterpret_cast<float4*>(wr + b1) = n1;  cv1 = n1;

        rd = wr;
        if (i + 1 < steps) grid_barrier(ebase + (unsigned)i + 1u);
    }

    // Bump epoch base for the next launch/replay (epochs used: ebase+1 ..
    // ebase+steps-1). Next launch cannot start until this kernel retires.
    if (blockIdx.x == 0 && threadIdx.x == 0 && steps > 1) {
        g_epoch_base = ebase + (unsigned)steps - 1u;
    }
}

// ---------------- fallback per-step kernel (R2, passed @476us) ----------------
__global__ __launch_bounds__(256) void therapy_step(
    const float* __restrict__ src,
    const float* __restrict__ ther,
    float* __restrict__ dst,
    const float* __restrict__ Dp,
    const float* __restrict__ rhop,
    const float* __restrict__ dtp,
    const int* __restrict__ stepsp)
{
    const int tid = blockIdx.x * blockDim.x + threadIdx.x;

    const int xq = tid % NXQ;
    const int t2 = tid / NXQ;
    const int y  = t2 % NY;
    const int z0 = t2 / NY;             // 0..79
    const int base0 = tid * 4;          // group 0: z in [0,80)
    const int base1 = base0 + 80 * NPLANE;  // group 1: z in [80,160)

    const int offym = (y > 0)        ? -NX : 0;
    const int offyp = (y < NY - 1)   ?  NX : 0;
    const int offxl = (xq > 0)       ? -1  : 0;
    const int offxr = (xq < NXQ - 1) ?  4  : 3;
    const int offzm0 = (z0 > 0)      ? -NPLANE : 0;
    const int offzp1 = (z0 < 79)     ?  NPLANE : 0;

    const float4 cc0 = ld4(src + base0);
    const float4 cc1 = ld4(src + base1);
    float4 ym0 = ld4(src + base0 + offym);
    float4 ym1 = ld4(src + base1 + offym);
    float4 yp0 = ld4(src + base0 + offyp);
    float4 yp1 = ld4(src + base1 + offyp);
    float4 zm0 = ld4(src + base0 + offzm0);
    const float4 zm1 = ld4(src + base1 - NPLANE);
    const float4 zp0 = ld4(src + base0 + NPLANE);
    float4 zp1 = ld4(src + base1 + offzp1);
    float xl0 = src[base0 + offxl];
    float xl1 = src[base1 + offxl];
    float xr0 = src[base0 + offxr];
    float xr1 = src[base1 + offxr];
    const float4 tm0 = ld4(ther + base0);
    const float4 tm1 = ld4(ther + base1);

    const float D       = *Dp;
    const float rho     = *rhop;
    const float delta_t = *dtp / (float)(*stepsp);

    const float4 zero4 = make_float4(0.f, 0.f, 0.f, 0.f);
    if (y == 0)        { ym0 = zero4; ym1 = zero4; }
    if (y == NY - 1)   { yp0 = zero4; yp1 = zero4; }
    if (z0 == 0)       { zm0 = zero4; }
    if (z0 == 79)      { zp1 = zero4; }
    if (xq == 0)       { xl0 = 0.f; xl1 = 0.f; }
    if (xq == NXQ - 1) { xr0 = 0.f; xr1 = 0.f; }

    {
        const float lap0 = xl0   + cc0.y + ym0.x + yp0.x + zm0.x + zp0.x - 6.f * cc0.x;
        const float lap1 = cc0.x + cc0.z + ym0.y + yp0.y + zm0.y + zp0.y - 6.f * cc0.y;
        const float lap2 = cc0.y + cc0.w + ym0.z + yp0.z + zm0.z + zp0.z - 6.f * cc0.z;
        const float lap3 = cc0.z + xr0   + ym0.w + yp0.w + zm0.w + zp0.w - 6.f * cc0.w;
        float4 o;
        float g;
        g = D * lap0 + rho * cc0.x * (1.f - cc0.x) - 2.f * tm0.x * cc0.x;
        o.x = fminf(fmaxf(cc0.x + g * delta_t, 0.f), 1.f);
        g = D * lap1 + rho * cc0.y * (1.f - cc0.y) - 2.f * tm0.y * cc0.y;
        o.y = fminf(fmaxf(cc0.y + g * delta_t, 0.f), 1.f);
        g = D * lap2 + rho * cc0.z * (1.f - cc0.z) - 2.f * tm0.z * cc0.z;
        o.z = fminf(fmaxf(cc0.z + g * delta_t, 0.f), 1.f);
        g = D * lap3 + rho * cc0.w * (1.f - cc0.w) - 2.f * tm0.w * cc0.w;
        o.w = fminf(fmaxf(cc0.w + g * delta_t, 0.f), 1.f);
        *reinterpret_cast<float4*>(dst + base0) = o;
    }
    {
        const float lap0 = xl1   + cc1.y + ym1.x + yp1.x + zm1.x + zp1.x - 6.f * cc1.x;
        const float lap1 = cc1.x + cc1.z + ym1.y + yp1.y + zm1.y + zp1.y - 6.f * cc1.y;
        const float lap2 = cc1.y + cc1.w + ym1.z + yp1.z + zm1.z + zp1.z - 6.f * cc1.z;
        const float lap3 = cc1.z + xr1   + ym1.w + yp1.w + zm1.w + zp1.w - 6.f * cc1.w;
        float4 o;
        float g;
        g = D * lap0 + rho * cc1.x * (1.f - cc1.x) - 2.f * tm1.x * cc1.x;
        o.x = fminf(fmaxf(cc1.x + g * delta_t, 0.f), 1.f);
        g = D * lap1 + rho * cc1.y * (1.f - cc1.y) - 2.f * tm1.y * cc1.y;
        o.y = fminf(fmaxf(cc1.y + g * delta_t, 0.f), 1.f);
        g = D * lap2 + rho * cc1.z * (1.f - cc1.z) - 2.f * tm1.z * cc1.z;
        o.z = fminf(fmaxf(cc1.z + g * delta_t, 0.f), 1.f);
        g = D * lap3 + rho * cc1.w * (1.f - cc1.w) - 2.f * tm1.w * cc1.w;
        o.w = fminf(fmaxf(cc1.w + g * delta_t, 0.f), 1.f);
        *reinterpret_cast<float4*>(dst + base1) = o;
    }
}

extern "C" void kernel_launch(void* const* d_in, const int* in_sizes, int n_in,
                              void* d_out, int out_size, void* d_ws, size_t ws_size,
                              hipStream_t stream) {
    const float* c_init = (const float*)d_in[0];
    const float* Dp     = (const float*)d_in[1];
    const float* rhop   = (const float*)d_in[2];
    const float* dtp    = (const float*)d_in[3];
    const float* ther   = (const float*)d_in[4];
    const int*   stepsp = (const int*)d_in[5];

    float* out = (float*)d_out;
    float* wsA = (float*)d_ws;   // ping-pong buffer (16.4 MB)

    // ---- gate the cooperative path (computed once) ----
    static int coop_ok = -1;
    if (coop_ok < 0) {
        coop_ok = 0;
        int dev = 0;
        if (hipGetDevice(&dev) == hipSuccess) {
            int coopAttr = 0, ncu = 0, maxb = 0;
            if (hipDeviceGetAttribute(&coopAttr, hipDeviceAttributeCooperativeLaunch, dev) == hipSuccess &&
                coopAttr != 0 &&
                hipDeviceGetAttribute(&ncu, hipDeviceAttributeMultiprocessorCount, dev) == hipSuccess &&
                hipOccupancyMaxActiveBlocksPerMultiprocessor(
                    &maxb, (const void*)therapy_all, CT_BS, 0) == hipSuccess &&
                (long)maxb * (long)ncu >= (long)CT_NBLOCKS) {
                coop_ok = 1;
            }
        }
    }

    if (coop_ok == 1) {
        void* args[] = {
            (void*)&c_init, (void*)&ther, (void*)&out, (void*)&wsA,
            (void*)&Dp, (void*)&rhop, (void*)&dtp, (void*)&stepsp
        };
        if (hipLaunchCooperativeKernel((void*)therapy_all,
                                       dim3(CT_NBLOCKS), dim3(CT_BS),
                                       args, 0, stream) == hipSuccess) {
            return;
        }
        coop_ok = 0;  // launch rejected -> permanent fallback
    }

    // ---- fallback: 30 per-step launches (proven R2 path) ----
    const dim3 block(256);
    const dim3 grid(FB_NBLOCKS);
    const float* src = c_init;
    for (int i = 0; i < 30; ++i) {
        float* dst = (i & 1) ? out : wsA;
        therapy_step<<<grid, block, 0, stream>>>(src, ther, dst, Dp, rhop, dtp, stepsp);
        src = dst;
    }
}

// Round 6
// 474.721 us; speedup vs baseline: 1.0035x; 1.0035x over previous
//
#include <hip/hip_runtime.h>
#include <hip/hip_cooperative_groups.h>

namespace cg = cooperative_groups;

// 3D reaction-diffusion tumor solver, 160^3 f32 grid, 30 explicit Euler steps.
// R8: persistent cooperative kernel with NEIGHBOR-FLAG sync (no global barrier).
//
// R5-R7 post-mortem: at 96% occupancy and with all state register-resident the
// kernel was stuck at ~474 us = multi-launch parity. Counters: FETCH 5.3MB/step
// (L2 serves reads across fences), VALUBusy 3.6%, no pipe busy -> the ~10us/step
// is SERIAL global-barrier latency (arrive -> scan 1000 flags -> go -> observe,
// each an L3-scope round trip + slowest-block convergence). Fix: drop the grid
// barrier. Each block posts a monotone flag after each step and waits only on
// its 6 dependency blocks {+-1 (y/x rows), +-12,+-13 (z planes)}. Skew<=1
// between neighbors => triple-buffer the grid (ws, static g_mid, out; cycle
// aligned so step 29 lands in out). Flag base = block's own flag at entry
// (all flags advance steps/launch -> equal at entry -> replay-safe, no reset).

#define NX 160
#define NY 160
#define NZ 160
#define NXQ (NX / 4)              // 40 float4 groups per row
#define NPLANE (NX * NY)          // 25600 floats per z-plane
#define NGROUPS (NZ * NY * NXQ)   // 1,024,000 float4 groups

// --- cooperative config: 512-thread blocks, contiguous z-pairs ---
#define CT_BS 512
#define CT_NTHREADS (NGROUPS / 2)        // 512,000
#define CT_NBLOCKS (CT_NTHREADS / CT_BS) // 1000

// --- fallback config (R2): 2 groups/thread, strided halves ---
#define FB_NTHREADS (NGROUPS / 2)      // 512,000
#define FB_NBLOCKS (FB_NTHREADS / 256) // 2000

// ---- sync + buffer state (zero-init at module load) ----
__device__ unsigned int g_flag[CT_NBLOCKS * 16];  // one flag per 64B line
__device__ float g_mid[NGROUPS * 4];              // third grid buffer (16.4MB)

__device__ __forceinline__ float4 ld4(const float* p) {
    return *reinterpret_cast<const float4*>(p);
}

// ---------------- cooperative all-steps kernel ----------------
__global__ __launch_bounds__(CT_BS, 8) void therapy_all(
    const float* __restrict__ c_init,
    const float* __restrict__ ther,
    float* __restrict__ out,
    float* __restrict__ ws,
    const float* __restrict__ Dp,
    const float* __restrict__ rhop,
    const float* __restrict__ dtp,
    const int* __restrict__ stepsp)
{
    // Bijective XCD swizzle: each XCD owns a contiguous logical range
    // (contiguous z-slab) -> halo + flag traffic stays mostly XCD-local.
    const int lb  = (blockIdx.x & 7) * (CT_NBLOCKS / 8) + (blockIdx.x >> 3);
    const int tid = lb * CT_BS + threadIdx.x;

    const int xq = tid % NXQ;
    const int t2 = tid / NXQ;
    const int y  = t2 % NY;
    const int k  = t2 / NY;            // z-pair index, planes 2k and 2k+1

    const int   steps   = *stepsp;
    const float D       = *Dp;
    const float rho     = *rhop;
    const float delta_t = *dtp / (float)steps;

    // Flag base: my own flag at entry. Every block posts exactly `steps`
    // times per launch, so at entry all flags are equal -> consistent base
    // across blocks, monotone across graph replays, nothing to reset.
    const unsigned int fbase =
        __hip_atomic_load(&g_flag[lb * 16], __ATOMIC_RELAXED,
                          __HIP_MEMORY_SCOPE_AGENT);

    const int  offym = (y > 0)        ? -NX : 0;
    const int  offyp = (y < NY - 1)   ?  NX : 0;
    const int  offxl = (xq > 0)       ? -1  : 0;
    const int  offxr = (xq < NXQ - 1) ?  4  : 3;
    const bool mym = (y == 0), myp = (y == NY - 1);
    const bool mxl = (xq == 0), mxr = (xq == NXQ - 1);
    const bool mzm = (k == 0);                    // plane 2k   is z==0
    const bool mzp = (k == NZ / 2 - 1);           // plane 2k+1 is z==159
    const int  offzm = mzm ? 0 : -NPLANE;
    const int  offzp = mzp ? 0 :  NPLANE;

    const int b0 = (2 * k * NY + y) * NX + xq * 4;  // plane 2k
    const int b1 = b0 + NPLANE;                     // plane 2k+1

    // Persistent register state: therapy + current concentration.
    const float4 tv0 = ld4(ther + b0);
    const float4 tv1 = ld4(ther + b1);
    float4 cv0 = ld4(c_init + b0);
    float4 cv1 = ld4(c_init + b1);

    const float4 z4 = make_float4(0.f, 0.f, 0.f, 0.f);

    // Triple-buffer cycle; OFF aligns the cycle so step steps-1 hits bufs[0]=out.
    float* bufs[3] = { out, ws, g_mid };
    const int OFF = (3 - (steps - 1) % 3) % 3;

    // My 6 dependency blocks (clamped; self-clamp is trivially satisfied).
    const int dlt[6] = { -13, -12, -1, 1, 12, 13 };

    const float* rd = c_init;
    for (int i = 0; i < steps; ++i) {
        float* wr = bufs[(i + OFF) % 3];

        if (i > 0) {
            // Wait: 6 dependency blocks finished step i-1 (flag >= fbase+i).
            if (threadIdx.x < 6) {
                int nb = lb + dlt[threadIdx.x];
                nb = nb < 0 ? 0 : (nb >= CT_NBLOCKS ? CT_NBLOCKS - 1 : nb);
                const unsigned int tgt = fbase + (unsigned)i;
                while (__hip_atomic_load(&g_flag[nb * 16], __ATOMIC_RELAXED,
                                         __HIP_MEMORY_SCOPE_AGENT) < tgt) {
                    __builtin_amdgcn_s_sleep(2);
                }
            }
            __syncthreads();
            __builtin_amdgcn_fence(__ATOMIC_ACQUIRE, "agent");
        }

        // ---- all global loads up front (max MLP) ----
        float4 ym0 = ld4(rd + b0 + offym);
        float4 yp0 = ld4(rd + b0 + offyp);
        float4 ym1 = ld4(rd + b1 + offym);
        float4 yp1 = ld4(rd + b1 + offyp);
        float4 zmg = ld4(rd + b0 + offzm);   // plane 2k-1 (masked at z=0)
        float4 zpg = ld4(rd + b1 + offzp);   // plane 2k+2 (masked at z=159)
        float  xl0 = rd[b0 + offxl];
        float  xr0 = rd[b0 + offxr];
        float  xl1 = rd[b1 + offxl];
        float  xr1 = rd[b1 + offxr];

        if (mym) { ym0 = z4; ym1 = z4; }
        if (myp) { yp0 = z4; yp1 = z4; }
        if (mzm) zmg = z4;
        if (mzp) zpg = z4;
        if (mxl) { xl0 = 0.f; xl1 = 0.f; }
        if (mxr) { xr0 = 0.f; xr1 = 0.f; }

        // ---- group 0 (plane 2k): zm = zmg, zp = cv1 (register) ----
        float4 n0;
        {
            const float lap0 = xl0   + cv0.y + ym0.x + yp0.x + zmg.x + cv1.x - 6.f * cv0.x;
            const float lap1 = cv0.x + cv0.z + ym0.y + yp0.y + zmg.y + cv1.y - 6.f * cv0.y;
            const float lap2 = cv0.y + cv0.w + ym0.z + yp0.z + zmg.z + cv1.z - 6.f * cv0.z;
            const float lap3 = cv0.z + xr0   + ym0.w + yp0.w + zmg.w + cv1.w - 6.f * cv0.w;
            float g;
            g = D * lap0 + rho * cv0.x * (1.f - cv0.x) - 2.f * tv0.x * cv0.x;
            n0.x = fminf(fmaxf(cv0.x + g * delta_t, 0.f), 1.f);
            g = D * lap1 + rho * cv0.y * (1.f - cv0.y) - 2.f * tv0.y * cv0.y;
            n0.y = fminf(fmaxf(cv0.y + g * delta_t, 0.f), 1.f);
            g = D * lap2 + rho * cv0.z * (1.f - cv0.z) - 2.f * tv0.z * cv0.z;
            n0.z = fminf(fmaxf(cv0.z + g * delta_t, 0.f), 1.f);
            g = D * lap3 + rho * cv0.w * (1.f - cv0.w) - 2.f * tv0.w * cv0.w;
            n0.w = fminf(fmaxf(cv0.w + g * delta_t, 0.f), 1.f);
        }
        // ---- group 1 (plane 2k+1): zm = cv0 (register), zp = zpg ----
        float4 n1;
        {
            const float lap0 = xl1   + cv1.y + ym1.x + yp1.x + cv0.x + zpg.x - 6.f * cv1.x;
            const float lap1 = cv1.x + cv1.z + ym1.y + yp1.y + cv0.y + zpg.y - 6.f * cv1.y;
            const float lap2 = cv1.y + cv1.w + ym1.z + yp1.z + cv0.z + zpg.z - 6.f * cv1.z;
            const float lap3 = cv1.z + xr1   + ym1.w + yp1.w + cv0.w + zpg.w - 6.f * cv1.w;
            float g;
            g = D * lap0 + rho * cv1.x * (1.f - cv1.x) - 2.f * tv1.x * cv1.x;
            n1.x = fminf(fmaxf(cv1.x + g * delta_t, 0.f), 1.f);
            g = D * lap1 + rho * cv1.y * (1.f - cv1.y) - 2.f * tv1.y * cv1.y;
            n1.y = fminf(fmaxf(cv1.y + g * delta_t, 0.f), 1.f);
            g = D * lap2 + rho * cv1.z * (1.f - cv1.z) - 2.f * tv1.z * cv1.z;
            n1.z = fminf(fmaxf(cv1.z + g * delta_t, 0.f), 1.f);
            g = D * lap3 + rho * cv1.w * (1.f - cv1.w) - 2.f * tv1.w * cv1.w;
            n1.w = fminf(fmaxf(cv1.w + g * delta_t, 0.f), 1.f);
        }

        *reinterpret_cast<float4*>(wr + b0) = n0;  cv0 = n0;
        *reinterpret_cast<float4*>(wr + b1) = n1;  cv1 = n1;

        // Post my progress: stores drained by the release fence below
        // (__syncthreads lowers to a workgroup release incl. vmcnt(0)).
        __syncthreads();
        if (threadIdx.x == 0) {
            __hip_atomic_store(&g_flag[lb * 16], fbase + (unsigned)i + 1u,
                               __ATOMIC_RELEASE, __HIP_MEMORY_SCOPE_AGENT);
        }

        rd = wr;
    }
}

// ---------------- fallback per-step kernel (R2, passed @476us) ----------------
__global__ __launch_bounds__(256) void therapy_step(
    const float* __restrict__ src,
    const float* __restrict__ ther,
    float* __restrict__ dst,
    const float* __restrict__ Dp,
    const float* __restrict__ rhop,
    const float* __restrict__ dtp,
    const int* __restrict__ stepsp)
{
    const int tid = blockIdx.x * blockDim.x + threadIdx.x;

    const int xq = tid % NXQ;
    const int t2 = tid / NXQ;
    const int y  = t2 % NY;
    const int z0 = t2 / NY;             // 0..79
    const int base0 = tid * 4;          // group 0: z in [0,80)
    const int base1 = base0 + 80 * NPLANE;  // group 1: z in [80,160)

    const int offym = (y > 0)        ? -NX : 0;
    const int offyp = (y < NY - 1)   ?  NX : 0;
    const int offxl = (xq > 0)       ? -1  : 0;
    const int offxr = (xq < NXQ - 1) ?  4  : 3;
    const int offzm0 = (z0 > 0)      ? -NPLANE : 0;
    const int offzp1 = (z0 < 79)     ?  NPLANE : 0;

    const float4 cc0 = ld4(src + base0);
    const float4 cc1 = ld4(src + base1);
    float4 ym0 = ld4(src + base0 + offym);
    float4 ym1 = ld4(src + base1 + offym);
    float4 yp0 = ld4(src + base0 + offyp);
    float4 yp1 = ld4(src + base1 + offyp);
    float4 zm0 = ld4(src + base0 + offzm0);
    const float4 zm1 = ld4(src + base1 - NPLANE);
    const float4 zp0 = ld4(src + base0 + NPLANE);
    float4 zp1 = ld4(src + base1 + offzp1);
    float xl0 = src[base0 + offxl];
    float xl1 = src[base1 + offxl];
    float xr0 = src[base0 + offxr];
    float xr1 = src[base1 + offxr];
    const float4 tm0 = ld4(ther + base0);
    const float4 tm1 = ld4(ther + base1);

    const float D       = *Dp;
    const float rho     = *rhop;
    const float delta_t = *dtp / (float)(*stepsp);

    const float4 zero4 = make_float4(0.f, 0.f, 0.f, 0.f);
    if (y == 0)        { ym0 = zero4; ym1 = zero4; }
    if (y == NY - 1)   { yp0 = zero4; yp1 = zero4; }
    if (z0 == 0)       { zm0 = zero4; }
    if (z0 == 79)      { zp1 = zero4; }
    if (xq == 0)       { xl0 = 0.f; xl1 = 0.f; }
    if (xq == NXQ - 1) { xr0 = 0.f; xr1 = 0.f; }

    {
        const float lap0 = xl0   + cc0.y + ym0.x + yp0.x + zm0.x + zp0.x - 6.f * cc0.x;
        const float lap1 = cc0.x + cc0.z + ym0.y + yp0.y + zm0.y + zp0.y - 6.f * cc0.y;
        const float lap2 = cc0.y + cc0.w + ym0.z + yp0.z + zm0.z + zp0.z - 6.f * cc0.z;
        const float lap3 = cc0.z + xr0   + ym0.w + yp0.w + zm0.w + zp0.w - 6.f * cc0.w;
        float4 o;
        float g;
        g = D * lap0 + rho * cc0.x * (1.f - cc0.x) - 2.f * tm0.x * cc0.x;
        o.x = fminf(fmaxf(cc0.x + g * delta_t, 0.f), 1.f);
        g = D * lap1 + rho * cc0.y * (1.f - cc0.y) - 2.f * tm0.y * cc0.y;
        o.y = fminf(fmaxf(cc0.y + g * delta_t, 0.f), 1.f);
        g = D * lap2 + rho * cc0.z * (1.f - cc0.z) - 2.f * tm0.z * cc0.z;
        o.z = fminf(fmaxf(cc0.z + g * delta_t, 0.f), 1.f);
        g = D * lap3 + rho * cc0.w * (1.f - cc0.w) - 2.f * tm0.w * cc0.w;
        o.w = fminf(fmaxf(cc0.w + g * delta_t, 0.f), 1.f);
        *reinterpret_cast<float4*>(dst + base0) = o;
    }
    {
        const float lap0 = xl1   + cc1.y + ym1.x + yp1.x + zm1.x + zp1.x - 6.f * cc1.x;
        const float lap1 = cc1.x + cc1.z + ym1.y + yp1.y + zm1.y + zp1.y - 6.f * cc1.y;
        const float lap2 = cc1.y + cc1.w + ym1.z + yp1.z + zm1.z + zp1.z - 6.f * cc1.z;
        const float lap3 = cc1.z + xr1   + ym1.w + yp1.w + zm1.w + zp1.w - 6.f * cc1.w;
        float4 o;
        float g;
        g = D * lap0 + rho * cc1.x * (1.f - cc1.x) - 2.f * tm1.x * cc1.x;
        o.x = fminf(fmaxf(cc1.x + g * delta_t, 0.f), 1.f);
        g = D * lap1 + rho * cc1.y * (1.f - cc1.y) - 2.f * tm1.y * cc1.y;
        o.y = fminf(fmaxf(cc1.y + g * delta_t, 0.f), 1.f);
        g = D * lap2 + rho * cc1.z * (1.f - cc1.z) - 2.f * tm1.z * cc1.z;
        o.z = fminf(fmaxf(cc1.z + g * delta_t, 0.f), 1.f);
        g = D * lap3 + rho * cc1.w * (1.f - cc1.w) - 2.f * tm1.w * cc1.w;
        o.w = fminf(fmaxf(cc1.w + g * delta_t, 0.f), 1.f);
        *reinterpret_cast<float4*>(dst + base1) = o;
    }
}

extern "C" void kernel_launch(void* const* d_in, const int* in_sizes, int n_in,
                              void* d_out, int out_size, void* d_ws, size_t ws_size,
                              hipStream_t stream) {
    const float* c_init = (const float*)d_in[0];
    const float* Dp     = (const float*)d_in[1];
    const float* rhop   = (const float*)d_in[2];
    const float* dtp    = (const float*)d_in[3];
    const float* ther   = (const float*)d_in[4];
    const int*   stepsp = (const int*)d_in[5];

    float* out = (float*)d_out;
    float* wsA = (float*)d_ws;   // grid buffer (16.4 MB)

    // ---- gate the cooperative path (computed once) ----
    static int coop_ok = -1;
    if (coop_ok < 0) {
        coop_ok = 0;
        int dev = 0;
        if (hipGetDevice(&dev) == hipSuccess) {
            int coopAttr = 0, ncu = 0, maxb = 0;
            if (hipDeviceGetAttribute(&coopAttr, hipDeviceAttributeCooperativeLaunch, dev) == hipSuccess &&
                coopAttr != 0 &&
                hipDeviceGetAttribute(&ncu, hipDeviceAttributeMultiprocessorCount, dev) == hipSuccess &&
                hipOccupancyMaxActiveBlocksPerMultiprocessor(
                    &maxb, (const void*)therapy_all, CT_BS, 0) == hipSuccess &&
                (long)maxb * (long)ncu >= (long)CT_NBLOCKS) {
                coop_ok = 1;
            }
        }
    }

    if (coop_ok == 1) {
        void* args[] = {
            (void*)&c_init, (void*)&ther, (void*)&out, (void*)&wsA,
            (void*)&Dp, (void*)&rhop, (void*)&dtp, (void*)&stepsp
        };
        if (hipLaunchCooperativeKernel((void*)therapy_all,
                                       dim3(CT_NBLOCKS), dim3(CT_BS),
                                       args, 0, stream) == hipSuccess) {
            return;
        }
        coop_ok = 0;  // launch rejected -> permanent fallback
    }

    // ---- fallback: 30 per-step launches (proven R2 path) ----
    const dim3 block(256);
    const dim3 grid(FB_NBLOCKS);
    const float* src = c_init;
    for (int i = 0; i < 30; ++i) {
        float* dst = (i & 1) ? out : wsA;
        therapy_step<<<grid, block, 0, stream>>>(src, ther, dst, Dp, rhop, dtp, stepsp);
        src = dst;
    }
}